// Round 1
// baseline (3839.833 us; speedup 1.0000x reference)
//
#include <hip/hip_runtime.h>
#include <stdint.h>

typedef __attribute__((ext_vector_type(8))) short short8;
typedef __attribute__((ext_vector_type(4))) float f32x4;

struct alignas(16) I4 { int x, y, z, w; };
struct alignas(8)  U2 { unsigned x, y; };
struct alignas(16) F4 { float x, y, z, w; };

__device__ __forceinline__ unsigned short f2bf(float f) {
  unsigned u = __builtin_bit_cast(unsigned, f);
  u += 0x7FFFu + ((u >> 16) & 1u);
  return (unsigned short)(u >> 16);
}
__device__ __forceinline__ float bf2f(unsigned short h) {
  unsigned u = ((unsigned)h) << 16;
  return __builtin_bit_cast(float, u);
}
__device__ __forceinline__ float fast_tanh(float x) {
  float a = fabsf(x);
  float e = __expf(2.0f * a);
  float r = 1.0f - 2.0f / (e + 1.0f);
  return copysignf(r, x);
}

// ws layout (bytes):
//   0        : xa bf16 [S=512][B=64][H=512]            = 33,554,432
//   33554432 : W_ih bf16 [512][512]                    =    524,288
//   34078720 : W_hh bf16 [512][512]                    =    524,288
//   34603008 : hbuf fp32 [4 groups][2 parity][16][512] =    262,144
//   34865152 : cnt int   [4 groups][512 steps] (+pad)  =     16,384
#define XA_OFF   0
#define WIH_OFF  33554432
#define WHH_OFF  (33554432 + 524288)
#define HBUF_OFF (33554432 + 1048576)
#define CNT_OFF  (33554432 + 1048576 + 262144)
#define YSIZE    33554432ull

// ---------------- prep: cvt weights to bf16, zero hbuf + counters ----------
__global__ __launch_bounds__(256) void prep_kernel(
    const float* __restrict__ Wih, const float* __restrict__ Whh,
    unsigned short* __restrict__ WihB, unsigned short* __restrict__ WhhB,
    float* __restrict__ hbuf, int* __restrict__ cnt) {
  int t = blockIdx.x * 256 + threadIdx.x;  // grid = 1024*256 = 262144 exactly
  WihB[t] = f2bf(Wih[t]);
  WhhB[t] = f2bf(Whh[t]);
  if (t < 4 * 2 * 16 * 512) hbuf[t] = 0.0f;
  if (t < 4096) cnt[t] = 0;
}

// ---------------- gemm1: xa = x @ W_ih^T + b_ih + b_hh (bf16 MFMA) --------
#define G1S 40  // LDS row stride in shorts (32 + 8 pad -> 80B rows, 16B aligned)
__global__ __launch_bounds__(256) void gemm1_kernel(
    const float* __restrict__ x, const unsigned short* __restrict__ WihB,
    const float* __restrict__ bih, const float* __restrict__ bhh,
    unsigned short* __restrict__ xa) {
  __shared__ alignas(16) unsigned short Alds[128 * G1S];
  const int wg = blockIdx.x;            // 1024 wgs: 256 m-tiles x 4 n-tiles
  const int nt = wg & 3, mt = wg >> 2;
  const int tid = threadIdx.x;
  const int wave = tid >> 6, lane = tid & 63;
  const int wm = wave & 1, wn = wave >> 1;
  const int l15 = lane & 15, quad = lane >> 4;

  f32x4 acc[4][4] = {};

  const int arow = tid >> 1, ahalf = tid & 1;
  const float* aptr = x + (size_t)(mt * 128 + arow) * 512 + ahalf * 16;
  unsigned short* awr = Alds + arow * G1S + ahalf * 16;
  const int nbase = nt * 128 + wn * 64;

  for (int ks = 0; ks < 16; ++ks) {
    // stage A tile: fp32 -> bf16 into LDS
    const F4* ap = (const F4*)(aptr + ks * 32);
#pragma unroll
    for (int j = 0; j < 4; ++j) {
      F4 v = ap[j];
      U2 u;
      u.x = (unsigned)f2bf(v.x) | ((unsigned)f2bf(v.y) << 16);
      u.y = (unsigned)f2bf(v.z) | ((unsigned)f2bf(v.w) << 16);
      *(U2*)(awr + j * 4) = u;
    }
    __syncthreads();

    short8 bfrag[4];
#pragma unroll
    for (int ni = 0; ni < 4; ++ni) {
      const int n = nbase + ni * 16 + l15;
      bfrag[ni] = __builtin_bit_cast(
          short8, *(const I4*)(WihB + (size_t)n * 512 + ks * 32 + quad * 8));
    }
    short8 afrag[4];
#pragma unroll
    for (int mi = 0; mi < 4; ++mi) {
      const unsigned short* ard = Alds + (wm * 64 + mi * 16 + l15) * G1S + quad * 8;
      afrag[mi] = __builtin_bit_cast(short8, *(const I4*)ard);
    }
#pragma unroll
    for (int mi = 0; mi < 4; ++mi)
#pragma unroll
      for (int ni = 0; ni < 4; ++ni)
        acc[mi][ni] = __builtin_amdgcn_mfma_f32_16x16x32_bf16(
            afrag[mi], bfrag[ni], acc[mi][ni], 0, 0, 0);
    __syncthreads();
  }

  // epilogue: C[m,n] layout col=lane&15, row=quad*4+r; write xa[s][b][n]
#pragma unroll
  for (int ni = 0; ni < 4; ++ni) {
    const int n = nbase + ni * 16 + l15;
    const float bias = bih[n] + bhh[n];
#pragma unroll
    for (int mi = 0; mi < 4; ++mi) {
#pragma unroll
      for (int r = 0; r < 4; ++r) {
        int m = mt * 128 + wm * 64 + mi * 16 + quad * 4 + r;
        int b = m >> 9, s = m & 511;
        xa[(size_t)(s * 64 + b) * 512 + n] = f2bf(acc[mi][ni][r] + bias);
      }
    }
  }
}

// ---------------- rnn: 512 sequential steps, 4 groups x 8 slice-wgs -------
#define HS 520             // LDS h row stride in shorts (512+8 -> 1040B, 16B-mult)
#define PLANE (16 * HS)    // one bf16 plane (hi or lo)
__global__ __launch_bounds__(256) void rnn_kernel(
    const unsigned short* __restrict__ xa, const unsigned short* __restrict__ WhhB,
    float* __restrict__ hbuf, int* __restrict__ cnt, float* __restrict__ out) {
  __shared__ alignas(16) unsigned short hlds[2 * PLANE];
  const int wg = blockIdx.x;          // 32 wgs
  const int group = wg & 3;           // same group spread over 2 XCDs (%8 swizzle)
  const int slice = wg >> 2;          // 0..7 : 64-wide g slice
  const int tid = threadIdx.x;
  const int wave = tid >> 6, lane = tid & 63;
  const int l15 = lane & 15, quad = lane >> 4;
  const int gcol = slice * 64 + wave * 16 + l15;  // this lane's output column n
  const int seqbase = group * 16;

  // W_hh B-fragments resident in registers for all 512 steps:
  // B[k=quad*8+j][n=l15] = W_hh[n][k] -> row-n contiguous 16B loads
  short8 bfrag[16];
#pragma unroll
  for (int kt = 0; kt < 16; ++kt)
    bfrag[kt] = __builtin_bit_cast(
        short8, *(const I4*)(WhhB + (size_t)gcol * 512 + kt * 32 + quad * 8));

  float* hb0 = hbuf + group * (2 * 16 * 512);
  int* cnt_g = cnt + group * 512;

  const int srow = tid >> 4;          // 0..15
  const int scol = (tid & 15) * 32;   // element offset in a 512 row
  unsigned short* hwr = hlds + srow * HS + scol;
  unsigned short* lwr = hwr + PLANE;

  for (int t = 0; t < 512; ++t) {
    // ---- stage h[16][512] fp32 -> hi/lo bf16 planes in LDS ----
    {
      const float* src = hb0 + (t & 1) * (16 * 512) + srow * 512 + scol;
#pragma unroll
      for (int jj = 0; jj < 4; ++jj) {
        F4 v0 = ((const F4*)src)[2 * jj];
        F4 v1 = ((const F4*)src)[2 * jj + 1];
        float vs[8] = {v0.x, v0.y, v0.z, v0.w, v1.x, v1.y, v1.z, v1.w};
        unsigned h[8], l[8];
#pragma unroll
        for (int e = 0; e < 8; ++e) {
          unsigned short hs = f2bf(vs[e]);
          h[e] = hs;
          l[e] = f2bf(vs[e] - bf2f(hs));
        }
        I4 hv, lv;
        hv.x = (int)(h[0] | (h[1] << 16)); hv.y = (int)(h[2] | (h[3] << 16));
        hv.z = (int)(h[4] | (h[5] << 16)); hv.w = (int)(h[6] | (h[7] << 16));
        lv.x = (int)(l[0] | (l[1] << 16)); lv.y = (int)(l[2] | (l[3] << 16));
        lv.z = (int)(l[4] | (l[5] << 16)); lv.w = (int)(l[6] | (l[7] << 16));
        *(I4*)(hwr + jj * 8) = hv;
        *(I4*)(lwr + jj * 8) = lv;
      }
    }
    __syncthreads();

    // ---- acc = h_hi @ Wslice^T + h_lo @ Wslice^T (same resident B-frags) ----
    f32x4 acc = {};
    const unsigned short* ard = hlds + l15 * HS + quad * 8;
#pragma unroll
    for (int kt = 0; kt < 16; ++kt) {
      short8 a = __builtin_bit_cast(short8, *(const I4*)(ard + kt * 32));
      acc = __builtin_amdgcn_mfma_f32_16x16x32_bf16(a, bfrag[kt], acc, 0, 0, 0);
    }
#pragma unroll
    for (int kt = 0; kt < 16; ++kt) {
      short8 a = __builtin_bit_cast(short8, *(const I4*)(ard + PLANE + kt * 32));
      acc = __builtin_amdgcn_mfma_f32_16x16x32_bf16(a, bfrag[kt], acc, 0, 0, 0);
    }

    // ---- epilogue: + xa, tanh, write h_new + y (both layers) ----
    const unsigned short* xrow = xa + ((size_t)t * 64 + seqbase) * 512 + gcol;
    float* dsth = hb0 + ((t + 1) & 1) * (16 * 512);
#pragma unroll
    for (int r = 0; r < 4; ++r) {
      const int m = quad * 4 + r;                 // C row = sequence index
      float pre = acc[r] + bf2f(xrow[m * 512]);
      float hv = fast_tanh(pre);
      dsth[m * 512 + gcol] = hv;
      const int b = seqbase + m;
      size_t ybase = ((size_t)b * 512 + t) * 1024 + gcol;
      out[ybase] = hv;
      out[ybase + 512] = hv;                      // layer 1 == layer 0
      if (t == 511) {
        out[YSIZE + (size_t)b * 1024 + gcol] = hv;
        out[YSIZE + (size_t)b * 1024 + 512 + gcol] = hv;
      }
    }

    // ---- inter-wg barrier (8 wgs of this group), per-step counter ----
    __threadfence();
    __syncthreads();
    if (tid == 0) {
      __hip_atomic_fetch_add(cnt_g + t, 1, __ATOMIC_RELEASE,
                             __HIP_MEMORY_SCOPE_AGENT);
      while (__hip_atomic_load(cnt_g + t, __ATOMIC_ACQUIRE,
                               __HIP_MEMORY_SCOPE_AGENT) < 8)
        __builtin_amdgcn_s_sleep(1);
    }
    __syncthreads();
  }
}

extern "C" void kernel_launch(void* const* d_in, const int* in_sizes, int n_in,
                              void* d_out, int out_size, void* d_ws, size_t ws_size,
                              hipStream_t stream) {
  (void)in_sizes; (void)n_in; (void)out_size; (void)ws_size;
  const float* x   = (const float*)d_in[0];
  const float* Wih = (const float*)d_in[1];
  const float* bih = (const float*)d_in[2];
  const float* Whh = (const float*)d_in[3];
  const float* bhh = (const float*)d_in[4];
  float* out = (float*)d_out;
  char* ws = (char*)d_ws;

  unsigned short* xaB  = (unsigned short*)(ws + XA_OFF);
  unsigned short* WihB = (unsigned short*)(ws + WIH_OFF);
  unsigned short* WhhB = (unsigned short*)(ws + WHH_OFF);
  float* hbuf          = (float*)(ws + HBUF_OFF);
  int* cnt             = (int*)(ws + CNT_OFF);

  prep_kernel<<<dim3(1024), dim3(256), 0, stream>>>(Wih, Whh, WihB, WhhB, hbuf, cnt);
  gemm1_kernel<<<dim3(1024), dim3(256), 0, stream>>>(x, WihB, bih, bhh, xaB);
  rnn_kernel<<<dim3(32), dim3(256), 0, stream>>>(xaB, WhhB, hbuf, cnt, out);
}

// Round 2
// 2897.441 us; speedup vs baseline: 1.3252x; 1.3252x over previous
//
#include <hip/hip_runtime.h>
#include <stdint.h>

typedef __attribute__((ext_vector_type(8))) short short8;
typedef __attribute__((ext_vector_type(4))) float f32x4;

struct alignas(16) I4 { int x, y, z, w; };
struct alignas(8)  U2 { unsigned x, y; };
struct alignas(16) F4 { float x, y, z, w; };

__device__ __forceinline__ unsigned short f2bf(float f) {
  unsigned u = __builtin_bit_cast(unsigned, f);
  u += 0x7FFFu + ((u >> 16) & 1u);
  return (unsigned short)(u >> 16);
}
__device__ __forceinline__ float bf2f(unsigned short h) {
  unsigned u = ((unsigned)h) << 16;
  return __builtin_bit_cast(float, u);
}
__device__ __forceinline__ float fast_tanh(float x) {
  float a = fabsf(x);
  float e = __expf(2.0f * a);
  float r = 1.0f - 2.0f / (e + 1.0f);
  return copysignf(r, x);
}

// ws layout (bytes):
//   0        : xa bf16 [S=512][B=64][H=512]            = 33,554,432
//   33554432 : W_ih bf16 [512][512]                    =    524,288
//   34078720 : W_hh bf16 [512][512]                    =    524,288
//   34603008 : hbuf fp32 [4 groups][2 parity][16][512] =    262,144
//   34865152 : flags int [4 groups][512 steps][8]      =     65,536
#define XA_OFF   0
#define WIH_OFF  33554432
#define WHH_OFF  (33554432 + 524288)
#define HBUF_OFF (33554432 + 1048576)
#define FLG_OFF  (33554432 + 1048576 + 262144)
#define YSIZE    33554432ull

// ---------------- prep: cvt weights to bf16, zero hbuf + flags -------------
__global__ __launch_bounds__(256) void prep_kernel(
    const float* __restrict__ Wih, const float* __restrict__ Whh,
    unsigned short* __restrict__ WihB, unsigned short* __restrict__ WhhB,
    float* __restrict__ hbuf, int* __restrict__ flg) {
  int t = blockIdx.x * 256 + threadIdx.x;  // grid = 1024*256 = 262144 exactly
  WihB[t] = f2bf(Wih[t]);
  WhhB[t] = f2bf(Whh[t]);
  if (t < 4 * 2 * 16 * 512) hbuf[t] = 0.0f;
  if (t < 4 * 512 * 8) flg[t] = 0;
}

// ---------------- gemm1: xa = x @ W_ih^T + b_ih + b_hh (bf16 MFMA) --------
#define G1S 40  // LDS row stride in shorts
__global__ __launch_bounds__(256) void gemm1_kernel(
    const float* __restrict__ x, const unsigned short* __restrict__ WihB,
    const float* __restrict__ bih, const float* __restrict__ bhh,
    unsigned short* __restrict__ xa) {
  __shared__ alignas(16) unsigned short Alds[128 * G1S];
  const int wg = blockIdx.x;            // 1024 wgs: 256 m-tiles x 4 n-tiles
  const int nt = wg & 3, mt = wg >> 2;
  const int tid = threadIdx.x;
  const int wave = tid >> 6, lane = tid & 63;
  const int wm = wave & 1, wn = wave >> 1;
  const int l15 = lane & 15, quad = lane >> 4;

  f32x4 acc[4][4] = {};

  const int arow = tid >> 1, ahalf = tid & 1;
  const float* aptr = x + (size_t)(mt * 128 + arow) * 512 + ahalf * 16;
  unsigned short* awr = Alds + arow * G1S + ahalf * 16;
  const int nbase = nt * 128 + wn * 64;

  for (int ks = 0; ks < 16; ++ks) {
    const F4* ap = (const F4*)(aptr + ks * 32);
#pragma unroll
    for (int j = 0; j < 4; ++j) {
      F4 v = ap[j];
      U2 u;
      u.x = (unsigned)f2bf(v.x) | ((unsigned)f2bf(v.y) << 16);
      u.y = (unsigned)f2bf(v.z) | ((unsigned)f2bf(v.w) << 16);
      *(U2*)(awr + j * 4) = u;
    }
    __syncthreads();

    short8 bfrag[4];
#pragma unroll
    for (int ni = 0; ni < 4; ++ni) {
      const int n = nbase + ni * 16 + l15;
      bfrag[ni] = __builtin_bit_cast(
          short8, *(const I4*)(WihB + (size_t)n * 512 + ks * 32 + quad * 8));
    }
    short8 afrag[4];
#pragma unroll
    for (int mi = 0; mi < 4; ++mi) {
      const unsigned short* ard = Alds + (wm * 64 + mi * 16 + l15) * G1S + quad * 8;
      afrag[mi] = __builtin_bit_cast(short8, *(const I4*)ard);
    }
#pragma unroll
    for (int mi = 0; mi < 4; ++mi)
#pragma unroll
      for (int ni = 0; ni < 4; ++ni)
        acc[mi][ni] = __builtin_amdgcn_mfma_f32_16x16x32_bf16(
            afrag[mi], bfrag[ni], acc[mi][ni], 0, 0, 0);
    __syncthreads();
  }

#pragma unroll
  for (int ni = 0; ni < 4; ++ni) {
    const int n = nbase + ni * 16 + l15;
    const float bias = bih[n] + bhh[n];
#pragma unroll
    for (int mi = 0; mi < 4; ++mi) {
#pragma unroll
      for (int r = 0; r < 4; ++r) {
        int m = mt * 128 + wm * 64 + mi * 16 + quad * 4 + r;
        int b = m >> 9, s = m & 511;
        xa[(size_t)(s * 64 + b) * 512 + n] = f2bf(acc[mi][ni][r] + bias);
      }
    }
  }
}

// ---------------- rnn: 512 sequential steps, 4 groups x 8 slice-wgs -------
// All cross-wg traffic uses relaxed agent-scope atomics (sc1: bypass the
// non-coherent per-XCD L2, hit the coherence point). NO fences anywhere:
// an agent-scope release fence on gfx950 = full buffer_wbl2 each step (this
// was the 7us/step in round 1). Ordering: __syncthreads drains vmcnt(0)
// before the flag store, so h stores are globally visible before the flag.
#define HS 520             // LDS h row stride in shorts (dwords/4 = 65, odd -> conflict-free b128)
#define PLANE (16 * HS)    // one bf16 plane (hi or lo)
__global__ __launch_bounds__(256) void rnn_kernel(
    const unsigned short* __restrict__ xa, const unsigned short* __restrict__ WhhB,
    float* __restrict__ hbuf, int* __restrict__ flg, float* __restrict__ out) {
  __shared__ alignas(16) unsigned short hlds[2 * PLANE];
  const int wg = blockIdx.x;          // 32 wgs
  const int group = wg & 3;
  const int slice = wg >> 2;          // 0..7 : 64-wide column slice
  const int tid = threadIdx.x;
  const int wave = tid >> 6, lane = tid & 63;
  const int l15 = lane & 15, quad = lane >> 4;
  const int gcol = slice * 64 + wave * 16 + l15;  // output column n
  const int seqbase = group * 16;

  // W_hh B-fragments resident in registers for all 512 steps
  short8 bfrag[16];
#pragma unroll
  for (int kt = 0; kt < 16; ++kt)
    bfrag[kt] = __builtin_bit_cast(
        short8, *(const I4*)(WhhB + (size_t)gcol * 512 + kt * 32 + quad * 8));

  float* hb0 = hbuf + group * (2 * 16 * 512);
  int* flg_g = flg + group * 512 * 8;

  const int srow = tid >> 4;          // 0..15 (row of h tile this thread stages)
  const int c15 = tid & 15;           // chunk lane within row

  for (int t = 0; t < 512; ++t) {
    // ---- wait for step t-1's h to be published (all waves poll in parallel)
    if (t > 0) {
      const int* fp = flg_g + (t - 1) * 8 + (lane & 7);
      for (;;) {
        int v = (lane < 8)
            ? __hip_atomic_load(fp, __ATOMIC_RELAXED, __HIP_MEMORY_SCOPE_AGENT)
            : 1;
        if (__all(v != 0)) break;
        __builtin_amdgcn_s_sleep(1);
      }
    }

    // ---- prefetch xa for this step (off critical path) ----
    const unsigned short* xrow = xa + ((size_t)t * 64 + seqbase) * 512 + gcol;
    float xv[4];
#pragma unroll
    for (int r = 0; r < 4; ++r) xv[r] = bf2f(xrow[(quad * 4 + r) * 512]);

    // ---- stage h[16][512] fp32 -> hi/lo bf16 planes in LDS (sc1 loads) ----
    {
      const float* src = hb0 + (t & 1) * (16 * 512) + srow * 512;
      unsigned short* dst = hlds + srow * HS;
#pragma unroll
      for (int jj = 0; jj < 4; ++jj) {
        const int c = jj * 16 + c15;          // chunk of 8 elems (conflict-free)
        const float* s8 = src + c * 8;
        float vs[8];
#pragma unroll
        for (int e = 0; e < 8; ++e)
          vs[e] = __hip_atomic_load(s8 + e, __ATOMIC_RELAXED,
                                    __HIP_MEMORY_SCOPE_AGENT);
        unsigned h[8], l[8];
#pragma unroll
        for (int e = 0; e < 8; ++e) {
          unsigned short hs = f2bf(vs[e]);
          h[e] = hs;
          l[e] = f2bf(vs[e] - bf2f(hs));
        }
        I4 hv, lv;
        hv.x = (int)(h[0] | (h[1] << 16)); hv.y = (int)(h[2] | (h[3] << 16));
        hv.z = (int)(h[4] | (h[5] << 16)); hv.w = (int)(h[6] | (h[7] << 16));
        lv.x = (int)(l[0] | (l[1] << 16)); lv.y = (int)(l[2] | (l[3] << 16));
        lv.z = (int)(l[4] | (l[5] << 16)); lv.w = (int)(l[6] | (l[7] << 16));
        *(I4*)(dst + c * 8) = hv;
        *(I4*)(dst + PLANE + c * 8) = lv;
      }
    }
    __syncthreads();

    // ---- two interleaved MFMA chains (hi/lo planes) ----
    f32x4 acch = {}, accl = {};
    const unsigned short* ard = hlds + l15 * HS + quad * 8;
#pragma unroll
    for (int kt = 0; kt < 16; ++kt) {
      short8 ah = __builtin_bit_cast(short8, *(const I4*)(ard + kt * 32));
      short8 al = __builtin_bit_cast(short8, *(const I4*)(ard + PLANE + kt * 32));
      acch = __builtin_amdgcn_mfma_f32_16x16x32_bf16(ah, bfrag[kt], acch, 0, 0, 0);
      accl = __builtin_amdgcn_mfma_f32_16x16x32_bf16(al, bfrag[kt], accl, 0, 0, 0);
    }

    // ---- epilogue: + xa, tanh; publish h_new (sc1), then flag, then y ----
    float* dsth = hb0 + ((t + 1) & 1) * (16 * 512);
    float hv[4];
#pragma unroll
    for (int r = 0; r < 4; ++r) {
      const int m = quad * 4 + r;                 // C row = sequence index
      float pre = acch[r] + accl[r] + xv[r];
      hv[r] = fast_tanh(pre);
      __hip_atomic_store(&dsth[m * 512 + gcol], hv[r], __ATOMIC_RELAXED,
                         __HIP_MEMORY_SCOPE_AGENT);
    }
    __syncthreads();          // drains vmcnt(0): h stores globally visible
    if (tid == 0)
      __hip_atomic_store(flg_g + t * 8 + slice, 1, __ATOMIC_RELAXED,
                         __HIP_MEMORY_SCOPE_AGENT);

    // y stores issue after the flag -> overlap the next step's poll
#pragma unroll
    for (int r = 0; r < 4; ++r) {
      const int b = seqbase + quad * 4 + r;
      size_t ybase = ((size_t)b * 512 + t) * 1024 + gcol;
      out[ybase] = hv[r];
      out[ybase + 512] = hv[r];                   // layer 1 == layer 0
      if (t == 511) {
        out[YSIZE + (size_t)b * 1024 + gcol] = hv[r];
        out[YSIZE + (size_t)b * 1024 + 512 + gcol] = hv[r];
      }
    }
  }
}

extern "C" void kernel_launch(void* const* d_in, const int* in_sizes, int n_in,
                              void* d_out, int out_size, void* d_ws, size_t ws_size,
                              hipStream_t stream) {
  (void)in_sizes; (void)n_in; (void)out_size; (void)ws_size;
  const float* x   = (const float*)d_in[0];
  const float* Wih = (const float*)d_in[1];
  const float* bih = (const float*)d_in[2];
  const float* Whh = (const float*)d_in[3];
  const float* bhh = (const float*)d_in[4];
  float* out = (float*)d_out;
  char* ws = (char*)d_ws;

  unsigned short* xaB  = (unsigned short*)(ws + XA_OFF);
  unsigned short* WihB = (unsigned short*)(ws + WIH_OFF);
  unsigned short* WhhB = (unsigned short*)(ws + WHH_OFF);
  float* hbuf          = (float*)(ws + HBUF_OFF);
  int* flg             = (int*)(ws + FLG_OFF);

  prep_kernel<<<dim3(1024), dim3(256), 0, stream>>>(Wih, Whh, WihB, WhhB, hbuf, flg);
  gemm1_kernel<<<dim3(1024), dim3(256), 0, stream>>>(x, WihB, bih, bhh, xaB);
  rnn_kernel<<<dim3(32), dim3(256), 0, stream>>>(xaB, WhhB, hbuf, flg, out);
}